// Round 12
// baseline (803.402 us; speedup 1.0000x reference)
//
#include <hip/hip_runtime.h>

#define H  64
#define TT 512
#define BB 512
#define CSTR 80   // hbuf chain stride in halves: 160B -> max 2-way bank aliasing

typedef _Float16 half8 __attribute__((ext_vector_type(8)));
typedef _Float16 half4 __attribute__((ext_vector_type(4)));
typedef float    f32x4 __attribute__((ext_vector_type(4)));

__device__ __forceinline__ float frcp(float x) { return __builtin_amdgcn_rcpf(x); }
__device__ __forceinline__ float sigm(float x) { return frcp(1.f + __expf(-x)); }
__device__ __forceinline__ float tanh_fast(float x) { return 1.f - 2.f * frcp(__expf(2.f * x) + 1.f); }

// ---------------------------------------------------------------------------
// xpad: [B*T][32] fp16, cols 0..3 = x (fp32->fp16), cols 4..31 = 0.
// ---------------------------------------------------------------------------
__global__ __launch_bounds__(256) void xpad_prep(const float* __restrict__ x,
                                                 _Float16* __restrict__ xpad) {
    int gid = blockIdx.x * 256 + threadIdx.x;
    int row = gid >> 2, q = gid & 3;
    half8 v = {0,0,0,0,0,0,0,0};
    if (q == 0) {
        float4 xv = ((const float4*)x)[row];
        v[0] = (_Float16)xv.x; v[1] = (_Float16)xv.y;
        v[2] = (_Float16)xv.z; v[3] = (_Float16)xv.w;
    }
    *(half8*)(xpad + (size_t)row * 32 + q * 8) = v;
}

// ---------------------------------------------------------------------------
// prep_w: layer-1 Wih -> fp16, permuted so output col = unit*4 + gate.
// out[dir][unit*4+gate][k] = Wih_dir[gate*64+unit][k]
// ---------------------------------------------------------------------------
__global__ __launch_bounds__(256) void prep_w(const float* __restrict__ wf,
                                              const float* __restrict__ wb,
                                              _Float16* __restrict__ out) {
    int i = blockIdx.x * 256 + threadIdx.x;      // 0 .. 65535
    int dir  = i >> 15;
    int rem  = i & 32767;
    int rowp = rem >> 7;
    int k    = rem & 127;
    int unit = rowp >> 2;
    int gate = rowp & 3;
    const float* src = dir ? wb : wf;
    out[i] = (_Float16)src[(gate * 64 + unit) * 128 + k];
}

// ---------------------------------------------------------------------------
// Layer 0 (R11 structure, best measured): C=2 chains/block, 512 blocks ->
// 2 independent blocks/CU with independent barriers.
// ---------------------------------------------------------------------------
__global__ __launch_bounds__(256, 2) void lstm_l0(
    const _Float16* __restrict__ xpad,
    const float* __restrict__ WihF, const float* __restrict__ WhhF, const float* __restrict__ bF,
    const float* __restrict__ WihB, const float* __restrict__ WhhB, const float* __restrict__ bB,
    _Float16* __restrict__ out0)
{
    const int dir = blockIdx.x & 1;
    const int b0  = (blockIdx.x >> 1) * 2;
    const int tid = threadIdx.x;
    const int w = tid >> 6, l = tid & 63, m = l & 15, q = l >> 4;
    const int ch  = m & 1;
    const int ubo = (m >> 1) & 3;
    const int uo  = w * 16 + ubo * 4 + q;
    const bool act = (m < 8);

    const float* Wih = dir ? WihB : WihF;
    const float* Whh = dir ? WhhB : WhhF;
    const float* bia = dir ? bB   : bF;

    half8 Af[4][3];
    f32x4 bv[4];
#pragma unroll
    for (int ub = 0; ub < 4; ++ub) {
        const int wrow = (m & 3) * 64 + (w * 16 + ub * 4 + (m >> 2));
#pragma unroll
        for (int s = 0; s < 3; ++s) {
            half8 tmp;
            if (s < 2) {
                const float* src = Whh + wrow * 64 + s * 32 + q * 8;
#pragma unroll
                for (int j = 0; j < 8; ++j) tmp[j] = (_Float16)src[j];
            } else {
#pragma unroll
                for (int j = 0; j < 8; ++j) {
                    int k = q * 8 + j;
                    tmp[j] = (k < 4) ? (_Float16)Wih[wrow * 4 + k] : (_Float16)0.f;
                }
            }
            Af[ub][s] = tmp;
        }
        const int u = w * 16 + ub * 4 + q;
        bv[ub] = (f32x4){bia[u], bia[64 + u], bia[128 + u], bia[192 + u]};
    }

    __shared__ _Float16 hbuf[2][2][CSTR];
    for (int i = tid; i < 2 * 2 * CSTR / 2; i += 256) ((unsigned int*)hbuf)[i] = 0u;
    __syncthreads();

    float c = 0.f;
    const int dt = dir ? -1 : 1;
    int t = dir ? TT - 1 : 0;
    const _Float16* xrow = xpad + (size_t)(b0 + ch) * TT * 32 + q * 8;
    half8 ax = *(const half8*)(xrow + t * 32);
    int p = 0;

    for (int s = 0; s < TT; ++s) {
        int tn = t + ((s + 1 < TT) ? dt : 0);
        half8 axn = *(const half8*)(xrow + tn * 32);

        half8 ah0 = *(const half8*)&hbuf[p][ch][q * 8];
        half8 ah1 = *(const half8*)&hbuf[p][ch][32 + q * 8];

        f32x4 g_own;
#pragma unroll
        for (int ub = 0; ub < 4; ++ub) {
            f32x4 a = __builtin_amdgcn_mfma_f32_16x16x32_f16(Af[ub][2], ax,  bv[ub], 0, 0, 0);
            a       = __builtin_amdgcn_mfma_f32_16x16x32_f16(Af[ub][0], ah0, a, 0, 0, 0);
            a       = __builtin_amdgcn_mfma_f32_16x16x32_f16(Af[ub][1], ah1, a, 0, 0, 0);
            if (ub == ubo) g_own = a;
        }

        float e_i = sigm(g_own[0]), e_f = sigm(g_own[1]);
        float e_g = tanh_fast(g_own[2]), e_o = sigm(g_own[3]);
        c = e_f * c + e_i * e_g;
        float hh = e_o * tanh_fast(c);

        if (act) {
            out0[((size_t)(b0 + ch) * TT + t) * 128 + dir * 64 + uo] = (_Float16)hh;
            hbuf[p ^ 1][ch][uo] = (_Float16)hh;
        }
        __syncthreads();
        p ^= 1; t += dt; ax = axn;
    }
}

// ---------------------------------------------------------------------------
// xp GEMM (R2 structure, verified): xp[dir][m][n] = sum_k A[m'][k]*Wb[dir][n][k]
// fp16 in, fp32 acc, fp16 out; n = unit*4+gate. Block 256 = 4 waves; block
// tile 64m x 256n; wave: 16 n-tiles x 4 k-slices = 64 MFMAs.
// ---------------------------------------------------------------------------
__global__ __launch_bounds__(256) void xp_gemm(
    const _Float16* __restrict__ A,      // [B*T, 128] (out0)
    const _Float16* __restrict__ Wb,     // [2][256][128] permuted fp16
    _Float16* __restrict__ xpF, _Float16* __restrict__ xpB,
    int s, int Tc, int tcShift)
{
    const int dir  = blockIdx.y;
    const int mb   = blockIdx.x;
    const int w    = threadIdx.x >> 6;
    const int lane = threadIdx.x & 63;
    const int quad = lane >> 4;
    const int l16  = lane & 15;

    const int mbase = mb * 64 + w * 16;
    const int m     = mbase + l16;
    const int bb    = m >> tcShift;
    const int u     = m & (Tc - 1);
    const int t     = dir ? (TT - 1 - s * Tc - u) : (s * Tc + u);

    const _Float16* arow = A + (size_t)(bb * TT + t) * 128;
    const _Float16* wdir = Wb + (size_t)dir * 256 * 128;

    f32x4 acc[16];
#pragma unroll
    for (int nt = 0; nt < 16; ++nt) acc[nt] = (f32x4){0.f, 0.f, 0.f, 0.f};

#pragma unroll
    for (int kk = 0; kk < 4; ++kk) {
        half8 a = *(const half8*)(arow + kk * 32 + quad * 8);
#pragma unroll
        for (int nt = 0; nt < 16; ++nt) {
            half8 bf = *(const half8*)(wdir + (size_t)(nt * 16 + l16) * 128 + kk * 32 + quad * 8);
            acc[nt] = __builtin_amdgcn_mfma_f32_16x16x32_f16(a, bf, acc[nt], 0, 0, 0);
        }
    }

    __shared__ __align__(16) _Float16 c_sh[4][16][264];
#pragma unroll
    for (int nt = 0; nt < 16; ++nt)
#pragma unroll
        for (int i = 0; i < 4; ++i)
            c_sh[w][quad * 4 + i][nt * 16 + l16] = (_Float16)acc[nt][i];
    __syncthreads();

    _Float16* dst = (dir ? xpB : xpF) + (size_t)mbase * 256;
#pragma unroll
    for (int rd = 0; rd < 8; ++rd) {
        int ci  = rd * 64 + lane;
        int row = ci >> 5;
        int off = ci & 31;
        float4 v = *(const float4*)((const char*)&c_sh[w][row][0] + off * 16);
        *(float4*)((char*)dst + (size_t)row * 512 + off * 16) = v;
    }
}

// ---------------------------------------------------------------------------
// Layer 1 recurrent: K = 64 (h only) -> 8 MFMAs/wave/step. x-projection comes
// from xp as the accumulator init (half4 load/lane/step, prefetched).
// C=2 chains/block, 512 blocks = 2 independent blocks/CU (R11 interleave).
// ---------------------------------------------------------------------------
__global__ __launch_bounds__(256, 2) void lstm_l1_rec(
    const _Float16* __restrict__ xpF, const _Float16* __restrict__ xpB,
    const float* __restrict__ WhhF, const float* __restrict__ bF,
    const float* __restrict__ WhhB, const float* __restrict__ bB,
    float* __restrict__ state,        // [3][1024*64] : h, c, hsum
    float* __restrict__ pooled,
    int Tc, int first, int last)
{
    const int dir = blockIdx.x & 1;
    const int b0  = (blockIdx.x >> 1) * 2;
    const int tid = threadIdx.x;
    const int w = tid >> 6, l = tid & 63, m = l & 15, q = l >> 4;
    const int ch  = m & 1;
    const int ubo = (m >> 1) & 3;
    const int uo  = w * 16 + ubo * 4 + q;
    const bool act = (m < 8);

    const float* Whh = dir ? WhhB : WhhF;
    const float* bia = dir ? bB   : bF;

    half8 Ah[4][2];
#pragma unroll
    for (int ub = 0; ub < 4; ++ub) {
        const int wrow = (m & 3) * 64 + (w * 16 + ub * 4 + (m >> 2));
#pragma unroll
        for (int s2 = 0; s2 < 2; ++s2) {
            const float* src = Whh + wrow * 64 + s2 * 32 + q * 8;
            half8 tmp;
#pragma unroll
            for (int j = 0; j < 8; ++j) tmp[j] = (_Float16)src[j];
            Ah[ub][s2] = tmp;
        }
    }
    const f32x4 bv = (f32x4){bia[uo], bia[64 + uo], bia[128 + uo], bia[192 + uo]};

    const int cell = ((b0 + ch) * 2 + dir) * 64 + uo;
    float* st_h = state;
    float* st_c = state + 1024 * 64;
    float* st_s = state + 2 * 1024 * 64;

    float c, hs, h0;
    if (first) { c = 0.f; hs = 0.f; h0 = 0.f; }
    else       { c = st_c[cell]; hs = st_s[cell]; h0 = st_h[cell]; }

    __shared__ _Float16 hbuf[2][2][CSTR];
    if (act) hbuf[0][ch][uo] = (_Float16)h0;
    __syncthreads();

    const _Float16* xrow = (dir ? xpB : xpF) + (size_t)(b0 + ch) * Tc * 256 + uo * 4;
    half4 xv = *(const half4*)xrow;
    float hlast = h0;
    int p = 0;

    for (int u = 0; u < Tc; ++u) {
        int un = (u + 1 < Tc) ? (u + 1) : u;
        half4 xn = *(const half4*)(xrow + (size_t)un * 256);

        half8 ah0 = *(const half8*)&hbuf[p][ch][q * 8];
        half8 ah1 = *(const half8*)&hbuf[p][ch][32 + q * 8];

        f32x4 cin;
        cin[0] = (float)xv[0] + bv[0];
        cin[1] = (float)xv[1] + bv[1];
        cin[2] = (float)xv[2] + bv[2];
        cin[3] = (float)xv[3] + bv[3];

        f32x4 g_own;
#pragma unroll
        for (int ub = 0; ub < 4; ++ub) {
            f32x4 a = __builtin_amdgcn_mfma_f32_16x16x32_f16(Ah[ub][0], ah0, cin, 0, 0, 0);
            a       = __builtin_amdgcn_mfma_f32_16x16x32_f16(Ah[ub][1], ah1, a, 0, 0, 0);
            if (ub == ubo) g_own = a;
        }

        float e_i = sigm(g_own[0]), e_f = sigm(g_own[1]);
        float e_g = tanh_fast(g_own[2]), e_o = sigm(g_own[3]);
        c = e_f * c + e_i * e_g;
        float hh = e_o * tanh_fast(c);
        hs += hh;
        hlast = hh;

        if (act) hbuf[p ^ 1][ch][uo] = (_Float16)hh;
        __syncthreads();
        p ^= 1; xv = xn;
    }

    if (act) {
        if (last) {
            pooled[(size_t)(b0 + ch) * 128 + dir * 64 + uo] = hs;
        } else {
            st_h[cell] = hlast; st_c[cell] = c; st_s[cell] = hs;
        }
    }
}

// ---------------------------------------------------------------------------
// Head: out[b] = dot(pooled[b], fcw) / T + fcb
// ---------------------------------------------------------------------------
__global__ __launch_bounds__(64) void fc_head(
    const float* __restrict__ pooled,
    const float* __restrict__ fcw, const float* __restrict__ fcb,
    float* __restrict__ out)
{
    const int b = blockIdx.x;
    const int l = threadIdx.x;
    float v = pooled[b * 128 + l] * fcw[l] + pooled[b * 128 + 64 + l] * fcw[64 + l];
#pragma unroll
    for (int o = 32; o > 0; o >>= 1) v += __shfl_down(v, o);
    if (l == 0) out[b] = v * (1.f / (float)TT) + fcb[0];
}

extern "C" void kernel_launch(void* const* d_in, const int* in_sizes, int n_in,
                              void* d_out, int out_size, void* d_ws, size_t ws_size,
                              hipStream_t stream) {
    const float* x       = (const float*)d_in[0];
    const float* Wih_l0f = (const float*)d_in[1];
    const float* Whh_l0f = (const float*)d_in[2];
    const float* b_l0f   = (const float*)d_in[3];
    const float* Wih_l0b = (const float*)d_in[4];
    const float* Whh_l0b = (const float*)d_in[5];
    const float* b_l0b   = (const float*)d_in[6];
    const float* Wih_l1f = (const float*)d_in[7];
    const float* Whh_l1f = (const float*)d_in[8];
    const float* b_l1f   = (const float*)d_in[9];
    const float* Wih_l1b = (const float*)d_in[10];
    const float* Whh_l1b = (const float*)d_in[11];
    const float* b_l1b   = (const float*)d_in[12];
    const float* fcw     = (const float*)d_in[13];
    const float* fcb     = (const float*)d_in[14];

    // ws layout
    const size_t o_xpad   = 0;                                   // 16.8 MB
    const size_t o_out0   = o_xpad + (size_t)BB * TT * 32 * 2;   // +67.1 MB
    const size_t o_wb     = o_out0 + (size_t)BB * TT * 128 * 2;  // +131 KB
    const size_t o_state  = o_wb + (size_t)2 * 256 * 128 * 2;    // +786 KB
    const size_t o_pooled = o_state + (size_t)3 * 1024 * 64 * 4; // +262 KB
    const size_t o_xp     = o_pooled + (size_t)BB * 128 * 4;

    _Float16* xpad   = (_Float16*)((char*)d_ws + o_xpad);
    _Float16* out0   = (_Float16*)((char*)d_ws + o_out0);
    _Float16* Wb     = (_Float16*)((char*)d_ws + o_wb);
    float*    state  = (float*)((char*)d_ws + o_state);
    float*    pooled = (float*)((char*)d_ws + o_pooled);

    int Tc = 512;
    while (Tc > 32) {
        size_t xpb = (size_t)BB * Tc * 256 * 2;
        if (o_xp + 2 * xpb <= ws_size) break;
        Tc >>= 1;
    }
    const size_t xpb = (size_t)BB * Tc * 256 * 2;
    _Float16* xpF = (_Float16*)((char*)d_ws + o_xp);
    _Float16* xpB = (_Float16*)((char*)d_ws + o_xp + xpb);
    int tcShift = 0; while ((1 << tcShift) < Tc) ++tcShift;
    const int nStages = TT / Tc;

    xpad_prep<<<(BB * TT * 4) / 256, 256, 0, stream>>>(x, xpad);
    prep_w<<<256, 256, 0, stream>>>(Wih_l1f, Wih_l1b, Wb);
    lstm_l0<<<(BB / 2) * 2, 256, 0, stream>>>(xpad, Wih_l0f, Whh_l0f, b_l0f,
                                              Wih_l0b, Whh_l0b, b_l0b, out0);
    for (int s = 0; s < nStages; ++s) {
        dim3 grid((BB * Tc) / 64, 2);
        xp_gemm<<<grid, 256, 0, stream>>>(out0, Wb, xpF, xpB, s, Tc, tcShift);
        lstm_l1_rec<<<(BB / 2) * 2, 256, 0, stream>>>(xpF, xpB, Whh_l1f, b_l1f,
                                                      Whh_l1b, b_l1b, state, pooled,
                                                      Tc, s == 0, s == nStages - 1);
    }
    fc_head<<<BB, 64, 0, stream>>>(pooled, fcw, fcb, (float*)d_out);
}

// Round 13
// 677.530 us; speedup vs baseline: 1.1858x; 1.1858x over previous
//
#include <hip/hip_runtime.h>

#define H  64
#define TT 512
#define BB 512
#define CSTR 80   // hbuf chain stride in halves: 160B -> max 2-way bank aliasing

typedef _Float16 half8 __attribute__((ext_vector_type(8)));
typedef float    f32x4 __attribute__((ext_vector_type(4)));

__device__ __forceinline__ float frcp(float x) { return __builtin_amdgcn_rcpf(x); }
__device__ __forceinline__ float sigm(float x) { return frcp(1.f + __expf(-x)); }
__device__ __forceinline__ float tanh_fast(float x) { return 1.f - 2.f * frcp(__expf(2.f * x) + 1.f); }

// ---------------------------------------------------------------------------
// xpad: [B*T][32] fp16, cols 0..3 = x (fp32->fp16), cols 4..31 = 0.
// ---------------------------------------------------------------------------
__global__ __launch_bounds__(256) void xpad_prep(const float* __restrict__ x,
                                                 _Float16* __restrict__ xpad) {
    int gid = blockIdx.x * 256 + threadIdx.x;
    int row = gid >> 2, q = gid & 3;
    half8 v = {0,0,0,0,0,0,0,0};
    if (q == 0) {
        float4 xv = ((const float4*)x)[row];
        v[0] = (_Float16)xv.x; v[1] = (_Float16)xv.y;
        v[2] = (_Float16)xv.z; v[3] = (_Float16)xv.w;
    }
    *(half8*)(xpad + (size_t)row * 32 + q * 8) = v;
}

// ---------------------------------------------------------------------------
// Layer 0 (R11 structure) + anti-phase stagger: half the blocks delay ~880 cyc
// at entry so co-resident blocks on a CU run MFMA-phase against VALU-phase
// (R11 counters: MfmaUtil+VALUBusy = 98.3% -> phase-locked pipe serialization;
// max instead of sum is the win). Pair flag (bit0 ^ bit8) differs within the
// co-resident pair for both plausible block->CU mappings.
// ---------------------------------------------------------------------------
__global__ __launch_bounds__(256, 2) void lstm_l0(
    const _Float16* __restrict__ xpad,
    const float* __restrict__ WihF, const float* __restrict__ WhhF, const float* __restrict__ bF,
    const float* __restrict__ WihB, const float* __restrict__ WhhB, const float* __restrict__ bB,
    _Float16* __restrict__ out0)
{
    const int dir = blockIdx.x & 1;
    const int b0  = (blockIdx.x >> 1) * 2;
    const int tid = threadIdx.x;
    const int w = tid >> 6, l = tid & 63, m = l & 15, q = l >> 4;
    const int ch  = m & 1;
    const int ubo = (m >> 1) & 3;
    const int uo  = w * 16 + ubo * 4 + q;
    const bool act = (m < 8);

    const float* Wih = dir ? WihB : WihF;
    const float* Whh = dir ? WhhB : WhhF;
    const float* bia = dir ? bB   : bF;

    half8 Af[4][3];
    f32x4 bv[4];
#pragma unroll
    for (int ub = 0; ub < 4; ++ub) {
        const int wrow = (m & 3) * 64 + (w * 16 + ub * 4 + (m >> 2));
#pragma unroll
        for (int s = 0; s < 3; ++s) {
            half8 tmp;
            if (s < 2) {
                const float* src = Whh + wrow * 64 + s * 32 + q * 8;
#pragma unroll
                for (int j = 0; j < 8; ++j) tmp[j] = (_Float16)src[j];
            } else {
#pragma unroll
                for (int j = 0; j < 8; ++j) {
                    int k = q * 8 + j;
                    tmp[j] = (k < 4) ? (_Float16)Wih[wrow * 4 + k] : (_Float16)0.f;
                }
            }
            Af[ub][s] = tmp;
        }
        const int u = w * 16 + ub * 4 + q;
        bv[ub] = (f32x4){bia[u], bia[64 + u], bia[128 + u], bia[192 + u]};
    }

    __shared__ _Float16 hbuf[2][2][CSTR];
    for (int i = tid; i < 2 * 2 * CSTR / 2; i += 256) ((unsigned int*)hbuf)[i] = 0u;

    // anti-phase stagger: ~160 dependent FMAs ~ 640 cyc (half of l0's ~1250 step)
    {
        int dly = ((blockIdx.x ^ (blockIdx.x >> 8)) & 1) * 160;
        float z = (float)(tid + 1);
#pragma unroll 1
        for (int i = 0; i < dly; ++i) z = __builtin_fmaf(z, 0.9999999f, 1.0e-7f);
        if (z > 1.0e30f) hbuf[0][0][CSTR - 1] = (_Float16)z;   // never true; defeats DCE
    }
    __syncthreads();

    float c = 0.f;
    const int dt = dir ? -1 : 1;
    int t = dir ? TT - 1 : 0;
    const _Float16* xrow = xpad + (size_t)(b0 + ch) * TT * 32 + q * 8;
    half8 ax = *(const half8*)(xrow + t * 32);
    int p = 0;

    for (int s = 0; s < TT; ++s) {
        int tn = t + ((s + 1 < TT) ? dt : 0);
        half8 axn = *(const half8*)(xrow + tn * 32);

        half8 ah0 = *(const half8*)&hbuf[p][ch][q * 8];
        half8 ah1 = *(const half8*)&hbuf[p][ch][32 + q * 8];

        f32x4 g_own;
#pragma unroll
        for (int ub = 0; ub < 4; ++ub) {
            f32x4 a = __builtin_amdgcn_mfma_f32_16x16x32_f16(Af[ub][2], ax,  bv[ub], 0, 0, 0);
            a       = __builtin_amdgcn_mfma_f32_16x16x32_f16(Af[ub][0], ah0, a, 0, 0, 0);
            a       = __builtin_amdgcn_mfma_f32_16x16x32_f16(Af[ub][1], ah1, a, 0, 0, 0);
            if (ub == ubo) g_own = a;
        }

        float e_i = sigm(g_own[0]), e_f = sigm(g_own[1]);
        float e_g = tanh_fast(g_own[2]), e_o = sigm(g_own[3]);
        c = e_f * c + e_i * e_g;
        float hh = e_o * tanh_fast(c);

        if (act) {
            out0[((size_t)(b0 + ch) * TT + t) * 128 + dir * 64 + uo] = (_Float16)hh;
            hbuf[p ^ 1][ch][uo] = (_Float16)hh;
        }
        __syncthreads();
        p ^= 1; t += dt; ax = axn;
    }
}

// ---------------------------------------------------------------------------
// Layer 1 (R11 structure) + anti-phase stagger (~880 cyc = half of 1771 step).
// ---------------------------------------------------------------------------
__global__ __launch_bounds__(256, 2) void lstm_l1(
    const _Float16* __restrict__ out0,
    const float* __restrict__ WihF, const float* __restrict__ WhhF, const float* __restrict__ bF,
    const float* __restrict__ WihB, const float* __restrict__ WhhB, const float* __restrict__ bB,
    float* __restrict__ pooled)
{
    const int dir = blockIdx.x & 1;
    const int b0  = (blockIdx.x >> 1) * 2;
    const int tid = threadIdx.x;
    const int w = tid >> 6, l = tid & 63, m = l & 15, q = l >> 4;
    const int ch  = m & 1;
    const int ubo = (m >> 1) & 3;
    const int uo  = w * 16 + ubo * 4 + q;
    const bool act = (m < 8);

    const float* Wih = dir ? WihB : WihF;
    const float* Whh = dir ? WhhB : WhhF;
    const float* bia = dir ? bB   : bF;

    half8 Af[4][6];          // [ub][0,1]=Whh, [2..5]=Wih
    f32x4 bv[4];
#pragma unroll
    for (int ub = 0; ub < 4; ++ub) {
        const int wrow = (m & 3) * 64 + (w * 16 + ub * 4 + (m >> 2));
#pragma unroll
        for (int s = 0; s < 6; ++s) {
            const float* src = (s < 2) ? (Whh + wrow * 64 + s * 32 + q * 8)
                                       : (Wih + wrow * 128 + (s - 2) * 32 + q * 8);
            half8 tmp;
#pragma unroll
            for (int j = 0; j < 8; ++j) tmp[j] = (_Float16)src[j];
            Af[ub][s] = tmp;
        }
        const int u = w * 16 + ub * 4 + q;
        bv[ub] = (f32x4){bia[u], bia[64 + u], bia[128 + u], bia[192 + u]};
    }

    __shared__ _Float16 hbuf[2][2][CSTR];
    for (int i = tid; i < 2 * 2 * CSTR / 2; i += 256) ((unsigned int*)hbuf)[i] = 0u;

    // anti-phase stagger: ~220 dependent FMAs ~ 880 cyc (half of l1's 1771 step)
    {
        int dly = ((blockIdx.x ^ (blockIdx.x >> 8)) & 1) * 220;
        float z = (float)(tid + 1);
#pragma unroll 1
        for (int i = 0; i < dly; ++i) z = __builtin_fmaf(z, 0.9999999f, 1.0e-7f);
        if (z > 1.0e30f) hbuf[0][0][CSTR - 1] = (_Float16)z;
    }
    __syncthreads();

    float c = 0.f, hs = 0.f;
    const int dt = dir ? -1 : 1;
    int t = dir ? TT - 1 : 0;
    const _Float16* xrow = out0 + (size_t)(b0 + ch) * TT * 128 + q * 8;

    half8 ax[4];
#pragma unroll
    for (int s4 = 0; s4 < 4; ++s4) ax[s4] = *(const half8*)(xrow + t * 128 + s4 * 32);
    int p = 0;

    for (int s = 0; s < TT; ++s) {
        int tn = t + ((s + 1 < TT) ? dt : 0);
        half8 axn[4];
#pragma unroll
        for (int s4 = 0; s4 < 4; ++s4) axn[s4] = *(const half8*)(xrow + tn * 128 + s4 * 32);

        half8 ah0 = *(const half8*)&hbuf[p][ch][q * 8];
        half8 ah1 = *(const half8*)&hbuf[p][ch][32 + q * 8];

        f32x4 g_own;
#pragma unroll
        for (int ub = 0; ub < 4; ++ub) {
            f32x4 a = bv[ub];
            a = __builtin_amdgcn_mfma_f32_16x16x32_f16(Af[ub][2], ax[0], a, 0, 0, 0);
            a = __builtin_amdgcn_mfma_f32_16x16x32_f16(Af[ub][3], ax[1], a, 0, 0, 0);
            a = __builtin_amdgcn_mfma_f32_16x16x32_f16(Af[ub][4], ax[2], a, 0, 0, 0);
            a = __builtin_amdgcn_mfma_f32_16x16x32_f16(Af[ub][5], ax[3], a, 0, 0, 0);
            a = __builtin_amdgcn_mfma_f32_16x16x32_f16(Af[ub][0], ah0,   a, 0, 0, 0);
            a = __builtin_amdgcn_mfma_f32_16x16x32_f16(Af[ub][1], ah1,   a, 0, 0, 0);
            if (ub == ubo) g_own = a;
        }

        float e_i = sigm(g_own[0]), e_f = sigm(g_own[1]);
        float e_g = tanh_fast(g_own[2]), e_o = sigm(g_own[3]);
        c = e_f * c + e_i * e_g;
        float hh = e_o * tanh_fast(c);
        hs += hh;

        if (act) hbuf[p ^ 1][ch][uo] = (_Float16)hh;
        __syncthreads();
        p ^= 1; t += dt;
#pragma unroll
        for (int s4 = 0; s4 < 4; ++s4) ax[s4] = axn[s4];
    }

    if (act) pooled[(size_t)(b0 + ch) * 128 + dir * 64 + uo] = hs;
}

// ---------------------------------------------------------------------------
// Head: out[b] = dot(pooled[b], fcw) / T + fcb
// ---------------------------------------------------------------------------
__global__ __launch_bounds__(64) void fc_head(
    const float* __restrict__ pooled,
    const float* __restrict__ fcw, const float* __restrict__ fcb,
    float* __restrict__ out)
{
    const int b = blockIdx.x;
    const int l = threadIdx.x;
    float v = pooled[b * 128 + l] * fcw[l] + pooled[b * 128 + 64 + l] * fcw[64 + l];
#pragma unroll
    for (int o = 32; o > 0; o >>= 1) v += __shfl_down(v, o);
    if (l == 0) out[b] = v * (1.f / (float)TT) + fcb[0];
}

extern "C" void kernel_launch(void* const* d_in, const int* in_sizes, int n_in,
                              void* d_out, int out_size, void* d_ws, size_t ws_size,
                              hipStream_t stream) {
    const float* x       = (const float*)d_in[0];
    const float* Wih_l0f = (const float*)d_in[1];
    const float* Whh_l0f = (const float*)d_in[2];
    const float* b_l0f   = (const float*)d_in[3];
    const float* Wih_l0b = (const float*)d_in[4];
    const float* Whh_l0b = (const float*)d_in[5];
    const float* b_l0b   = (const float*)d_in[6];
    const float* Wih_l1f = (const float*)d_in[7];
    const float* Whh_l1f = (const float*)d_in[8];
    const float* b_l1f   = (const float*)d_in[9];
    const float* Wih_l1b = (const float*)d_in[10];
    const float* Whh_l1b = (const float*)d_in[11];
    const float* b_l1b   = (const float*)d_in[12];
    const float* fcw     = (const float*)d_in[13];
    const float* fcb     = (const float*)d_in[14];

    const size_t o_xpad   = 0;
    const size_t o_out0   = o_xpad + (size_t)BB * TT * 32 * 2;
    const size_t o_pooled = o_out0 + (size_t)BB * TT * 128 * 2;

    _Float16* xpad   = (_Float16*)((char*)d_ws + o_xpad);
    _Float16* out0   = (_Float16*)((char*)d_ws + o_out0);
    float*    pooled = (float*)((char*)d_ws + o_pooled);

    xpad_prep<<<(BB * TT * 4) / 256, 256, 0, stream>>>(x, xpad);
    lstm_l0<<<(BB / 2) * 2, 256, 0, stream>>>(xpad, Wih_l0f, Whh_l0f, b_l0f,
                                              Wih_l0b, Whh_l0b, b_l0b, out0);
    lstm_l1<<<(BB / 2) * 2, 256, 0, stream>>>(out0, Wih_l1f, Whh_l1f, b_l1f,
                                              Wih_l1b, Whh_l1b, b_l1b, pooled);
    fc_head<<<BB, 64, 0, stream>>>(pooled, fcw, fcb, (float*)d_out);
}

// Round 14
// 578.618 us; speedup vs baseline: 1.3885x; 1.1709x over previous
//
#include <hip/hip_runtime.h>

#define H  64
#define TT 512
#define BB 512
#define CSTR 80   // hbuf chain stride in halves: 160B -> max 2-way bank aliasing
#define UCH 32    // chunk length (steps) for fused xp GEMM
#define XSTR 264  // xp row stride in halves (528B) -> de-phased banks

typedef _Float16 half8 __attribute__((ext_vector_type(8)));
typedef _Float16 half4 __attribute__((ext_vector_type(4)));
typedef float    f32x4 __attribute__((ext_vector_type(4)));

__device__ __forceinline__ float frcp(float x) { return __builtin_amdgcn_rcpf(x); }
__device__ __forceinline__ float sigm(float x) { return frcp(1.f + __expf(-x)); }
__device__ __forceinline__ float tanh_fast(float x) { return 1.f - 2.f * frcp(__expf(2.f * x) + 1.f); }

// ---------------------------------------------------------------------------
// xpad: [B*T][32] fp16, cols 0..3 = x (fp32->fp16), cols 4..31 = 0.
// ---------------------------------------------------------------------------
__global__ __launch_bounds__(256) void xpad_prep(const float* __restrict__ x,
                                                 _Float16* __restrict__ xpad) {
    int gid = blockIdx.x * 256 + threadIdx.x;
    int row = gid >> 2, q = gid & 3;
    half8 v = {0,0,0,0,0,0,0,0};
    if (q == 0) {
        float4 xv = ((const float4*)x)[row];
        v[0] = (_Float16)xv.x; v[1] = (_Float16)xv.y;
        v[2] = (_Float16)xv.z; v[3] = (_Float16)xv.w;
    }
    *(half8*)(xpad + (size_t)row * 32 + q * 8) = v;
}

// ---------------------------------------------------------------------------
// Layer 0 (R11 structure, best measured; stagger removed - neutral).
// ---------------------------------------------------------------------------
__global__ __launch_bounds__(256, 2) void lstm_l0(
    const _Float16* __restrict__ xpad,
    const float* __restrict__ WihF, const float* __restrict__ WhhF, const float* __restrict__ bF,
    const float* __restrict__ WihB, const float* __restrict__ WhhB, const float* __restrict__ bB,
    _Float16* __restrict__ out0)
{
    const int dir = blockIdx.x & 1;
    const int b0  = (blockIdx.x >> 1) * 2;
    const int tid = threadIdx.x;
    const int w = tid >> 6, l = tid & 63, m = l & 15, q = l >> 4;
    const int ch  = m & 1;
    const int ubo = (m >> 1) & 3;
    const int uo  = w * 16 + ubo * 4 + q;
    const bool act = (m < 8);

    const float* Wih = dir ? WihB : WihF;
    const float* Whh = dir ? WhhB : WhhF;
    const float* bia = dir ? bB   : bF;

    half8 Af[4][3];
    f32x4 bv[4];
#pragma unroll
    for (int ub = 0; ub < 4; ++ub) {
        const int wrow = (m & 3) * 64 + (w * 16 + ub * 4 + (m >> 2));
#pragma unroll
        for (int s = 0; s < 3; ++s) {
            half8 tmp;
            if (s < 2) {
                const float* src = Whh + wrow * 64 + s * 32 + q * 8;
#pragma unroll
                for (int j = 0; j < 8; ++j) tmp[j] = (_Float16)src[j];
            } else {
#pragma unroll
                for (int j = 0; j < 8; ++j) {
                    int k = q * 8 + j;
                    tmp[j] = (k < 4) ? (_Float16)Wih[wrow * 4 + k] : (_Float16)0.f;
                }
            }
            Af[ub][s] = tmp;
        }
        const int u = w * 16 + ub * 4 + q;
        bv[ub] = (f32x4){bia[u], bia[64 + u], bia[128 + u], bia[192 + u]};
    }

    __shared__ _Float16 hbuf[2][2][CSTR];
    for (int i = tid; i < 2 * 2 * CSTR / 2; i += 256) ((unsigned int*)hbuf)[i] = 0u;
    __syncthreads();

    float c = 0.f;
    const int dt = dir ? -1 : 1;
    int t = dir ? TT - 1 : 0;
    const _Float16* xrow = xpad + (size_t)(b0 + ch) * TT * 32 + q * 8;
    half8 ax = *(const half8*)(xrow + t * 32);
    int p = 0;

    for (int s = 0; s < TT; ++s) {
        int tn = t + ((s + 1 < TT) ? dt : 0);
        half8 axn = *(const half8*)(xrow + tn * 32);

        half8 ah0 = *(const half8*)&hbuf[p][ch][q * 8];
        half8 ah1 = *(const half8*)&hbuf[p][ch][32 + q * 8];

        f32x4 g_own;
#pragma unroll
        for (int ub = 0; ub < 4; ++ub) {
            f32x4 a = __builtin_amdgcn_mfma_f32_16x16x32_f16(Af[ub][2], ax,  bv[ub], 0, 0, 0);
            a       = __builtin_amdgcn_mfma_f32_16x16x32_f16(Af[ub][0], ah0, a, 0, 0, 0);
            a       = __builtin_amdgcn_mfma_f32_16x16x32_f16(Af[ub][1], ah1, a, 0, 0, 0);
            if (ub == ubo) g_own = a;
        }

        float e_i = sigm(g_own[0]), e_f = sigm(g_own[1]);
        float e_g = tanh_fast(g_own[2]), e_o = sigm(g_own[3]);
        c = e_f * c + e_i * e_g;
        float hh = e_o * tanh_fast(c);

        if (act) {
            out0[((size_t)(b0 + ch) * TT + t) * 128 + dir * 64 + uo] = (_Float16)hh;
            hbuf[p ^ 1][ch][uo] = (_Float16)hh;
        }
        __syncthreads();
        p ^= 1; t += dt; ax = axn;
    }
}

// ---------------------------------------------------------------------------
// Layer 1 FUSED: alternating phases per 32-step chunk.
//  Phase A (GEMM): xp[ch][u][n] = out0[ch][t(u)][:] . Wih[perm(n)][:] into LDS.
//    M=16 time-steps (no replica waste), per wave: 2ch x 2sg x 4 gate-tiles
//    x 4 k-slices = 64 MFMAs per chunk = 2/step amortized (vs 16/step before).
//  Phase B (recurrence): 8 MFMAs/wave/step (h-part only); xp enters as the
//    accumulator init via one 8-B LDS read (R12-verified numerics).
//  n = unit*4+gate so lane (m,q) reads its cell's 4 gates as one half4.
// ---------------------------------------------------------------------------
__global__ __launch_bounds__(256, 2) void lstm_l1_fused(
    const _Float16* __restrict__ out0,
    const float* __restrict__ WihF, const float* __restrict__ WhhF, const float* __restrict__ bF,
    const float* __restrict__ WihB, const float* __restrict__ WhhB, const float* __restrict__ bB,
    float* __restrict__ pooled)
{
    const int dir = blockIdx.x & 1;
    const int b0  = (blockIdx.x >> 1) * 2;
    const int tid = threadIdx.x;
    const int w = tid >> 6, l = tid & 63, m = l & 15, q = l >> 4;
    const int ch  = m & 1;
    const int ubo = (m >> 1) & 3;
    const int uo  = w * 16 + ubo * 4 + q;
    const bool act = (m < 8);

    const float* Wih = dir ? WihB : WihF;
    const float* Whh = dir ? WhhB : WhhF;
    const float* bia = dir ? bB   : bF;

    // Recurrent weights (A-operand of phase-B MFMAs)
    half8 Ah[4][2];
#pragma unroll
    for (int ub = 0; ub < 4; ++ub) {
        const int wrow = (m & 3) * 64 + (w * 16 + ub * 4 + (m >> 2));
#pragma unroll
        for (int s2 = 0; s2 < 2; ++s2) {
            const float* src = Whh + wrow * 64 + s2 * 32 + q * 8;
            half8 tmp;
#pragma unroll
            for (int j = 0; j < 8; ++j) tmp[j] = (_Float16)src[j];
            Ah[ub][s2] = tmp;
        }
    }
    const f32x4 bv = (f32x4){bia[uo], bia[64 + uo], bia[128 + uo], bia[192 + uo]};

    // GEMM weights (B-operand of phase-A MFMAs), persistent.
    // This wave owns output cols n = w*64 + j*16 + m; weight row = (n&3)*64+(n>>2).
    half8 Bg[4][4];
#pragma unroll
    for (int j = 0; j < 4; ++j) {
        const int n  = w * 64 + j * 16 + m;
        const int wr = (n & 3) * 64 + (n >> 2);
#pragma unroll
        for (int k4 = 0; k4 < 4; ++k4) {
            const float* src = Wih + wr * 128 + k4 * 32 + q * 8;
            half8 tmp;
#pragma unroll
            for (int jj = 0; jj < 8; ++jj) tmp[jj] = (_Float16)src[jj];
            Bg[j][k4] = tmp;
        }
    }

    __shared__ _Float16 xp[2][UCH][XSTR];     // 33.8 KB
    __shared__ _Float16 hbuf[2][2][CSTR];
    for (int i = tid; i < 2 * 2 * CSTR / 2; i += 256) ((unsigned int*)hbuf)[i] = 0u;
    __syncthreads();

    float c = 0.f, hs = 0.f;
    int p = 0;

    for (int chunk = 0; chunk < TT / UCH; ++chunk) {
        const int c0 = chunk * UCH;

        // ---------------- Phase A: xp GEMM into LDS ----------------
#pragma unroll
        for (int cc = 0; cc < 2; ++cc) {
#pragma unroll
            for (int sg = 0; sg < UCH / 16; ++sg) {
                const int ulocal = sg * 16 + m;                 // A row = this lane
                const int t = dir ? (TT - 1 - (c0 + ulocal)) : (c0 + ulocal);
                const _Float16* arow = out0 + (size_t)((b0 + cc) * TT + t) * 128 + q * 8;
                half8 a0 = *(const half8*)(arow);
                half8 a1 = *(const half8*)(arow + 32);
                half8 a2 = *(const half8*)(arow + 64);
                half8 a3 = *(const half8*)(arow + 96);
#pragma unroll
                for (int j = 0; j < 4; ++j) {
                    f32x4 acc = (f32x4){0.f, 0.f, 0.f, 0.f};
                    acc = __builtin_amdgcn_mfma_f32_16x16x32_f16(a0, Bg[j][0], acc, 0, 0, 0);
                    acc = __builtin_amdgcn_mfma_f32_16x16x32_f16(a1, Bg[j][1], acc, 0, 0, 0);
                    acc = __builtin_amdgcn_mfma_f32_16x16x32_f16(a2, Bg[j][2], acc, 0, 0, 0);
                    acc = __builtin_amdgcn_mfma_f32_16x16x32_f16(a3, Bg[j][3], acc, 0, 0, 0);
#pragma unroll
                    for (int i = 0; i < 4; ++i)
                        xp[cc][sg * 16 + q * 4 + i][w * 64 + j * 16 + m] = (_Float16)acc[i];
                }
            }
        }
        __syncthreads();

        // ---------------- Phase B: recurrence over the chunk ----------------
        half4 xv = *(const half4*)&xp[ch][0][uo * 4];
        for (int u = 0; u < UCH; ++u) {
            int un = (u + 1 < UCH) ? (u + 1) : u;
            half4 xn = *(const half4*)&xp[ch][un][uo * 4];

            half8 ah0 = *(const half8*)&hbuf[p][ch][q * 8];
            half8 ah1 = *(const half8*)&hbuf[p][ch][32 + q * 8];

            f32x4 cin;
            cin[0] = (float)xv[0] + bv[0];
            cin[1] = (float)xv[1] + bv[1];
            cin[2] = (float)xv[2] + bv[2];
            cin[3] = (float)xv[3] + bv[3];

            f32x4 g_own;
#pragma unroll
            for (int ub = 0; ub < 4; ++ub) {
                f32x4 a = __builtin_amdgcn_mfma_f32_16x16x32_f16(Ah[ub][0], ah0, cin, 0, 0, 0);
                a       = __builtin_amdgcn_mfma_f32_16x16x32_f16(Ah[ub][1], ah1, a, 0, 0, 0);
                if (ub == ubo) g_own = a;
            }

            float e_i = sigm(g_own[0]), e_f = sigm(g_own[1]);
            float e_g = tanh_fast(g_own[2]), e_o = sigm(g_own[3]);
            c = e_f * c + e_i * e_g;
            float hh = e_o * tanh_fast(c);
            hs += hh;

            if (act) hbuf[p ^ 1][ch][uo] = (_Float16)hh;
            __syncthreads();
            p ^= 1; xv = xn;
        }
    }

    if (act) pooled[(size_t)(b0 + ch) * 128 + dir * 64 + uo] = hs;
}

// ---------------------------------------------------------------------------
// Head: out[b] = dot(pooled[b], fcw) / T + fcb
// ---------------------------------------------------------------------------
__global__ __launch_bounds__(64) void fc_head(
    const float* __restrict__ pooled,
    const float* __restrict__ fcw, const float* __restrict__ fcb,
    float* __restrict__ out)
{
    const int b = blockIdx.x;
    const int l = threadIdx.x;
    float v = pooled[b * 128 + l] * fcw[l] + pooled[b * 128 + 64 + l] * fcw[64 + l];
#pragma unroll
    for (int o = 32; o > 0; o >>= 1) v += __shfl_down(v, o);
    if (l == 0) out[b] = v * (1.f / (float)TT) + fcb[0];
}

extern "C" void kernel_launch(void* const* d_in, const int* in_sizes, int n_in,
                              void* d_out, int out_size, void* d_ws, size_t ws_size,
                              hipStream_t stream) {
    const float* x       = (const float*)d_in[0];
    const float* Wih_l0f = (const float*)d_in[1];
    const float* Whh_l0f = (const float*)d_in[2];
    const float* b_l0f   = (const float*)d_in[3];
    const float* Wih_l0b = (const float*)d_in[4];
    const float* Whh_l0b = (const float*)d_in[5];
    const float* b_l0b   = (const float*)d_in[6];
    const float* Wih_l1f = (const float*)d_in[7];
    const float* Whh_l1f = (const float*)d_in[8];
    const float* b_l1f   = (const float*)d_in[9];
    const float* Wih_l1b = (const float*)d_in[10];
    const float* Whh_l1b = (const float*)d_in[11];
    const float* b_l1b   = (const float*)d_in[12];
    const float* fcw     = (const float*)d_in[13];
    const float* fcb     = (const float*)d_in[14];

    const size_t o_xpad   = 0;
    const size_t o_out0   = o_xpad + (size_t)BB * TT * 32 * 2;
    const size_t o_pooled = o_out0 + (size_t)BB * TT * 128 * 2;

    _Float16* xpad   = (_Float16*)((char*)d_ws + o_xpad);
    _Float16* out0   = (_Float16*)((char*)d_ws + o_out0);
    float*    pooled = (float*)((char*)d_ws + o_pooled);

    xpad_prep<<<(BB * TT * 4) / 256, 256, 0, stream>>>(x, xpad);
    lstm_l0<<<(BB / 2) * 2, 256, 0, stream>>>(xpad, Wih_l0f, Whh_l0f, b_l0f,
                                              Wih_l0b, Whh_l0b, b_l0b, out0);
    lstm_l1_fused<<<(BB / 2) * 2, 256, 0, stream>>>(out0, Wih_l1f, Whh_l1f, b_l1f,
                                                    Wih_l1b, Whh_l1b, b_l1b, pooled);
    fc_head<<<BB, 64, 0, stream>>>(pooled, fcw, fcb, (float*)d_out);
}

// Round 15
// 480.761 us; speedup vs baseline: 1.6711x; 1.2035x over previous
//
#include <hip/hip_runtime.h>

#define H  64
#define TT 512
#define BB 512
#define CSTR 80    // hbuf chain stride in halves: 160B -> max 2-way bank aliasing
#define UCH 16     // chunk length (steps) for fused xp GEMM (= one M-tile)
#define XSTRF 260  // xp row stride in floats: 4*260 % 32 == 16 -> 2-way writes (free)

typedef _Float16 half8 __attribute__((ext_vector_type(8)));
typedef float    f32x4 __attribute__((ext_vector_type(4)));

__device__ __forceinline__ float frcp(float x) { return __builtin_amdgcn_rcpf(x); }
__device__ __forceinline__ float sigm(float x) { return frcp(1.f + __expf(-x)); }
__device__ __forceinline__ float tanh_fast(float x) { return 1.f - 2.f * frcp(__expf(2.f * x) + 1.f); }

// ---------------------------------------------------------------------------
// xpad: [B*T][32] fp16, cols 0..3 = x (fp32->fp16), cols 4..31 = 0.
// ---------------------------------------------------------------------------
__global__ __launch_bounds__(256) void xpad_prep(const float* __restrict__ x,
                                                 _Float16* __restrict__ xpad) {
    int gid = blockIdx.x * 256 + threadIdx.x;
    int row = gid >> 2, q = gid & 3;
    half8 v = {0,0,0,0,0,0,0,0};
    if (q == 0) {
        float4 xv = ((const float4*)x)[row];
        v[0] = (_Float16)xv.x; v[1] = (_Float16)xv.y;
        v[2] = (_Float16)xv.z; v[3] = (_Float16)xv.w;
    }
    *(half8*)(xpad + (size_t)row * 32 + q * 8) = v;
}

// ---------------------------------------------------------------------------
// Layer 0 FUSED (R14 scheme extended to l0): per 16-step chunk,
//  Phase A: xp[cc][u][n] = xpad[t(u)][:32] . Wih0[perm(n)] + bias  (fp32, LDS)
//    K=4 (padded to 32): 1 MFMA per (cc,j) = 8/chunk/wave = 0.5/step amortized.
//    xp cols are WAVE-PRIVATE (wave w owns cols w*64..w*64+63) -> no barriers.
//  Phase B: 8 MFMAs/wave/step (h-part only), cin = float4 LDS read (bias and
//    x already inside). 2 independent blocks/CU (R11 interleave).
// ---------------------------------------------------------------------------
__global__ __launch_bounds__(256, 2) void lstm_l0(
    const _Float16* __restrict__ xpad,
    const float* __restrict__ WihF, const float* __restrict__ WhhF, const float* __restrict__ bF,
    const float* __restrict__ WihB, const float* __restrict__ WhhB, const float* __restrict__ bB,
    _Float16* __restrict__ out0)
{
    const int dir = blockIdx.x & 1;
    const int b0  = (blockIdx.x >> 1) * 2;
    const int tid = threadIdx.x;
    const int w = tid >> 6, l = tid & 63, m = l & 15, q = l >> 4;
    const int ch  = m & 1;
    const int ubo = (m >> 1) & 3;
    const int uo  = w * 16 + ubo * 4 + q;
    const bool act = (m < 8);

    const float* Wih = dir ? WihB : WihF;
    const float* Whh = dir ? WhhB : WhhF;
    const float* bia = dir ? bB   : bF;

    // Recurrent weights (A-operand of phase-B MFMAs)
    half8 Ah[4][2];
#pragma unroll
    for (int ub = 0; ub < 4; ++ub) {
        const int wrow = (m & 3) * 64 + (w * 16 + ub * 4 + (m >> 2));
#pragma unroll
        for (int s2 = 0; s2 < 2; ++s2) {
            const float* src = Whh + wrow * 64 + s2 * 32 + q * 8;
            half8 tmp;
#pragma unroll
            for (int j = 0; j < 8; ++j) tmp[j] = (_Float16)src[j];
            Ah[ub][s2] = tmp;
        }
    }

    // Phase-A weights (B-operand): col n = w*64+j*16+m -> weight row (n&3)*64+(n>>2)
    half8 Bg[4];
    float bvj[4];
#pragma unroll
    for (int j = 0; j < 4; ++j) {
        const int n  = w * 64 + j * 16 + m;
        const int gr = (n & 3) * 64 + (n >> 2);
        bvj[j] = bia[gr];
        half8 tmp;
#pragma unroll
        for (int jj = 0; jj < 8; ++jj) {
            int k = q * 8 + jj;
            tmp[jj] = (k < 4) ? (_Float16)Wih[gr * 4 + k] : (_Float16)0.f;
        }
        Bg[j] = tmp;
    }

    __shared__ __align__(16) float xp[2][UCH][XSTRF];   // 33.3 KB, wave-private cols
    __shared__ _Float16 hbuf[2][2][CSTR];
    for (int i = tid; i < 2 * 2 * CSTR / 2; i += 256) ((unsigned int*)hbuf)[i] = 0u;
    __syncthreads();

    float c = 0.f;
    int p = 0;

    for (int chunk = 0; chunk < TT / UCH; ++chunk) {
        const int c0 = chunk * UCH;

        // Phase A (no barrier: wave-private xp cols)
#pragma unroll
        for (int cc = 0; cc < 2; ++cc) {
            const int tA = dir ? (TT - 1 - (c0 + m)) : (c0 + m);
            half8 a0 = *(const half8*)(xpad + (size_t)((b0 + cc) * TT + tA) * 32 + q * 8);
#pragma unroll
            for (int j = 0; j < 4; ++j) {
                f32x4 acc = {bvj[j], bvj[j], bvj[j], bvj[j]};
                acc = __builtin_amdgcn_mfma_f32_16x16x32_f16(a0, Bg[j], acc, 0, 0, 0);
#pragma unroll
                for (int i = 0; i < 4; ++i)
                    xp[cc][q * 4 + i][w * 64 + j * 16 + m] = acc[i];
            }
        }

        // Phase B
        f32x4 xv = *(const f32x4*)&xp[ch][0][uo * 4];
        for (int u = 0; u < UCH; ++u) {
            int un = (u + 1 < UCH) ? (u + 1) : u;
            f32x4 xn = *(const f32x4*)&xp[ch][un][uo * 4];

            half8 ah0 = *(const half8*)&hbuf[p][ch][q * 8];
            half8 ah1 = *(const half8*)&hbuf[p][ch][32 + q * 8];

            f32x4 g_own;
#pragma unroll
            for (int ub = 0; ub < 4; ++ub) {
                f32x4 a = __builtin_amdgcn_mfma_f32_16x16x32_f16(Ah[ub][0], ah0, xv, 0, 0, 0);
                a       = __builtin_amdgcn_mfma_f32_16x16x32_f16(Ah[ub][1], ah1, a, 0, 0, 0);
                if (ub == ubo) g_own = a;
            }

            float e_i = sigm(g_own[0]), e_f = sigm(g_own[1]);
            float e_g = tanh_fast(g_own[2]), e_o = sigm(g_own[3]);
            c = e_f * c + e_i * e_g;
            float hh = e_o * tanh_fast(c);

            if (act) {
                const int tg = dir ? (TT - 1 - (c0 + u)) : (c0 + u);
                out0[((size_t)(b0 + ch) * TT + tg) * 128 + dir * 64 + uo] = (_Float16)hh;
                hbuf[p ^ 1][ch][uo] = (_Float16)hh;
            }
            __syncthreads();
            p ^= 1; xv = xn;
        }
    }
}

// ---------------------------------------------------------------------------
// Layer 1 FUSED (R14 + fp32 xp + bias folded + wave-private phase A):
//  Phase A: K=128 -> 4 MFMA slices per (cc,j) = 32/chunk/wave = 2/step.
//  Phase B: 8 MFMAs/wave/step; cin = float4 LDS read. hsum for mean-pool.
// ---------------------------------------------------------------------------
__global__ __launch_bounds__(256, 2) void lstm_l1(
    const _Float16* __restrict__ out0,
    const float* __restrict__ WihF, const float* __restrict__ WhhF, const float* __restrict__ bF,
    const float* __restrict__ WihB, const float* __restrict__ WhhB, const float* __restrict__ bB,
    float* __restrict__ pooled)
{
    const int dir = blockIdx.x & 1;
    const int b0  = (blockIdx.x >> 1) * 2;
    const int tid = threadIdx.x;
    const int w = tid >> 6, l = tid & 63, m = l & 15, q = l >> 4;
    const int ch  = m & 1;
    const int ubo = (m >> 1) & 3;
    const int uo  = w * 16 + ubo * 4 + q;
    const bool act = (m < 8);

    const float* Wih = dir ? WihB : WihF;
    const float* Whh = dir ? WhhB : WhhF;
    const float* bia = dir ? bB   : bF;

    half8 Ah[4][2];
#pragma unroll
    for (int ub = 0; ub < 4; ++ub) {
        const int wrow = (m & 3) * 64 + (w * 16 + ub * 4 + (m >> 2));
#pragma unroll
        for (int s2 = 0; s2 < 2; ++s2) {
            const float* src = Whh + wrow * 64 + s2 * 32 + q * 8;
            half8 tmp;
#pragma unroll
            for (int j = 0; j < 8; ++j) tmp[j] = (_Float16)src[j];
            Ah[ub][s2] = tmp;
        }
    }

    half8 Bg[4][4];
    float bvj[4];
#pragma unroll
    for (int j = 0; j < 4; ++j) {
        const int n  = w * 64 + j * 16 + m;
        const int gr = (n & 3) * 64 + (n >> 2);
        bvj[j] = bia[gr];
#pragma unroll
        for (int k4 = 0; k4 < 4; ++k4) {
            const float* src = Wih + gr * 128 + k4 * 32 + q * 8;
            half8 tmp;
#pragma unroll
            for (int jj = 0; jj < 8; ++jj) tmp[jj] = (_Float16)src[jj];
            Bg[j][k4] = tmp;
        }
    }

    __shared__ __align__(16) float xp[2][UCH][XSTRF];
    __shared__ _Float16 hbuf[2][2][CSTR];
    for (int i = tid; i < 2 * 2 * CSTR / 2; i += 256) ((unsigned int*)hbuf)[i] = 0u;
    __syncthreads();

    float c = 0.f, hs = 0.f;
    int p = 0;

    for (int chunk = 0; chunk < TT / UCH; ++chunk) {
        const int c0 = chunk * UCH;

        // Phase A (no barrier: wave-private xp cols)
#pragma unroll
        for (int cc = 0; cc < 2; ++cc) {
            const int tA = dir ? (TT - 1 - (c0 + m)) : (c0 + m);
            const _Float16* arow = out0 + (size_t)((b0 + cc) * TT + tA) * 128 + q * 8;
            half8 a0 = *(const half8*)(arow);
            half8 a1 = *(const half8*)(arow + 32);
            half8 a2 = *(const half8*)(arow + 64);
            half8 a3 = *(const half8*)(arow + 96);
#pragma unroll
            for (int j = 0; j < 4; ++j) {
                f32x4 acc = {bvj[j], bvj[j], bvj[j], bvj[j]};
                acc = __builtin_amdgcn_mfma_f32_16x16x32_f16(a0, Bg[j][0], acc, 0, 0, 0);
                acc = __builtin_amdgcn_mfma_f32_16x16x32_f16(a1, Bg[j][1], acc, 0, 0, 0);
                acc = __builtin_amdgcn_mfma_f32_16x16x32_f16(a2, Bg[j][2], acc, 0, 0, 0);
                acc = __builtin_amdgcn_mfma_f32_16x16x32_f16(a3, Bg[j][3], acc, 0, 0, 0);
#pragma unroll
                for (int i = 0; i < 4; ++i)
                    xp[cc][q * 4 + i][w * 64 + j * 16 + m] = acc[i];
            }
        }

        // Phase B
        f32x4 xv = *(const f32x4*)&xp[ch][0][uo * 4];
        for (int u = 0; u < UCH; ++u) {
            int un = (u + 1 < UCH) ? (u + 1) : u;
            f32x4 xn = *(const f32x4*)&xp[ch][un][uo * 4];

            half8 ah0 = *(const half8*)&hbuf[p][ch][q * 8];
            half8 ah1 = *(const half8*)&hbuf[p][ch][32 + q * 8];

            f32x4 g_own;
#pragma unroll
            for (int ub = 0; ub < 4; ++ub) {
                f32x4 a = __builtin_amdgcn_mfma_f32_16x16x32_f16(Ah[ub][0], ah0, xv, 0, 0, 0);
                a       = __builtin_amdgcn_mfma_f32_16x16x32_f16(Ah[ub][1], ah1, a, 0, 0, 0);
                if (ub == ubo) g_own = a;
            }

            float e_i = sigm(g_own[0]), e_f = sigm(g_own[1]);
            float e_g = tanh_fast(g_own[2]), e_o = sigm(g_own[3]);
            c = e_f * c + e_i * e_g;
            float hh = e_o * tanh_fast(c);
            hs += hh;

            if (act) hbuf[p ^ 1][ch][uo] = (_Float16)hh;
            __syncthreads();
            p ^= 1; xv = xn;
        }
    }

    if (act) pooled[(size_t)(b0 + ch) * 128 + dir * 64 + uo] = hs;
}

// ---------------------------------------------------------------------------
// Head: out[b] = dot(pooled[b], fcw) / T + fcb
// ---------------------------------------------------------------------------
__global__ __launch_bounds__(64) void fc_head(
    const float* __restrict__ pooled,
    const float* __restrict__ fcw, const float* __restrict__ fcb,
    float* __restrict__ out)
{
    const int b = blockIdx.x;
    const int l = threadIdx.x;
    float v = pooled[b * 128 + l] * fcw[l] + pooled[b * 128 + 64 + l] * fcw[64 + l];
#pragma unroll
    for (int o = 32; o > 0; o >>= 1) v += __shfl_down(v, o);
    if (l == 0) out[b] = v * (1.f / (float)TT) + fcb[0];
}

extern "C" void kernel_launch(void* const* d_in, const int* in_sizes, int n_in,
                              void* d_out, int out_size, void* d_ws, size_t ws_size,
                              hipStream_t stream) {
    const float* x       = (const float*)d_in[0];
    const float* Wih_l0f = (const float*)d_in[1];
    const float* Whh_l0f = (const float*)d_in[2];
    const float* b_l0f   = (const float*)d_in[3];
    const float* Wih_l0b = (const float*)d_in[4];
    const float* Whh_l0b = (const float*)d_in[5];
    const float* b_l0b   = (const float*)d_in[6];
    const float* Wih_l1f = (const float*)d_in[7];
    const float* Whh_l1f = (const float*)d_in[8];
    const float* b_l1f   = (const float*)d_in[9];
    const float* Wih_l1b = (const float*)d_in[10];
    const float* Whh_l1b = (const float*)d_in[11];
    const float* b_l1b   = (const float*)d_in[12];
    const float* fcw     = (const float*)d_in[13];
    const float* fcb     = (const float*)d_in[14];

    const size_t o_xpad   = 0;
    const size_t o_out0   = o_xpad + (size_t)BB * TT * 32 * 2;
    const size_t o_pooled = o_out0 + (size_t)BB * TT * 128 * 2;

    _Float16* xpad   = (_Float16*)((char*)d_ws + o_xpad);
    _Float16* out0   = (_Float16*)((char*)d_ws + o_out0);
    float*    pooled = (float*)((char*)d_ws + o_pooled);

    xpad_prep<<<(BB * TT * 4) / 256, 256, 0, stream>>>(x, xpad);
    lstm_l0<<<(BB / 2) * 2, 256, 0, stream>>>(xpad, Wih_l0f, Whh_l0f, b_l0f,
                                              Wih_l0b, Whh_l0b, b_l0b, out0);
    lstm_l1<<<(BB / 2) * 2, 256, 0, stream>>>(out0, Wih_l1f, Whh_l1f, b_l1f,
                                              Wih_l1b, Whh_l1b, b_l1b, pooled);
    fc_head<<<BB, 64, 0, stream>>>(pooled, fcw, fcb, (float*)d_out);
}